// Round 7
// baseline (257.476 us; speedup 1.0000x reference)
//
#include <hip/hip_runtime.h>

// EMA chunked scan + inverse-gather broadcast for DeChunkLayer (R16).
// R16 = R15 (phase-split fused, 205.0 us) + ONE variable: replace the
// warmup re-scan of chunk c-1 with R12's flag-gated lookback (now
// spill-free). x is read ONCE from HBM.
//
// Evidence: R10/R14/R15 (balance, occupancy, vmcnt-split) all null =>
// the kernel is not scheduling-limited; both structures (R11 2-kernel
// ~64 us, fused ~70 us) run ~1.6x their traffic floors. The largest
// REMOVABLE term is the warmup re-read: +64 MiB HBM (+25% of all bytes)
// plus a serial ~900cy-latency scan prologue per block. R12 proved the
// ticket/flag lookback correct on HW (passed; slow only via xv[32]-v4f
// spill @ VGPR=104 + scratch on the scan chain). R15 proved the v2f
// register-resident chunk scan fits (no spill). Combine them.
// Traffic: x 64 + Bbuf 2w+2r + out 128 NT ~= 196 MiB (vs R15 ~260).
// Predict: FETCH -60 MiB, VGPR 100-120 scratch 0, kernel ~70 -> 48-55
// => dur 205 -> 185-193 (beats R11 198.6). Pass-but->=205 => sync cost
// eats the win -> abandon fused, revert R11, probe cached-16B K2 stores.
//
// x: (1, 16384, 1024) f32, p_selected: (16384,) f32, b: (1, 32768) i32
// out: (1, 32768, 1024) f32
// z_t = (1-p_t) z_{t-1} + p_t x_t  (p clipped to [1e-4, 1-1e-4])
// out[f] = z[t] for f in [pos[t], pos[t+1])

#define DCH 1024
#define L_COMP 16384
#define L_FULL 32768
#define CHUNK 32
#define NCHUNK (L_COMP / CHUNK)   // 512
#define SEG (L_FULL / NCHUNK)     // 64 b-elements per segment
#define NTHR 512
#define EPSV 1e-4f
#define WMIN 1e-12f               // ~2^-40 lookback window (matches R11-R15)

typedef float v2f __attribute__((ext_vector_type(2)));

__device__ __forceinline__ float clipp(float p) {
    p = fmaxf(p, EPSV);
    return fminf(p, 1.0f - EPSV);
}

__global__ __launch_bounds__(NTHR, 4) void fused_kernel(
    const float* __restrict__ x, const float* __restrict__ p,
    const int* __restrict__ b, float* __restrict__ out,
    float* __restrict__ Bbuf, float* __restrict__ Apub,
    int* __restrict__ flag, int* __restrict__ ticket) {
    const int tid = threadIdx.x;
    const int lane = tid & 63;
    const int wave = tid >> 6;          // 0..7

    __shared__ int bpref[NCHUNK + 1];
    __shared__ int spos[CHUNK + 1];
    __shared__ int wtot[8];
    __shared__ int vcs;

    // Virtual block id = arrival order: lookback targets always running.
    if (tid == 0) vcs = atomicAdd(ticket, 1);
    __syncthreads();
    const int c = vcs;
    const int base = c * CHUNK;

    // (1) own-chunk burst load: 32 outstanding pure loads into registers.
    const v2f* x2 = reinterpret_cast<const v2f*>(x) + tid;
    v2f xv[CHUNK];   // 64 VGPR, static indexing only (rule #20)
#pragma unroll
    for (int j = 0; j < CHUNK; ++j)
        xv[j] = x2[(size_t)(base + j) * (DCH / 2)];

    // (2) local scan (zero init) in place; uniform scalar decay chain.
    float aprod = 1.0f;
    {
        v2f h = (v2f)0.f;
#pragma unroll
        for (int j = 0; j < CHUNK; ++j) {
            float pt = clipp(p[base + j]);   // uniform -> scalar load
            float a = 1.0f - pt;
            h = a * h + pt * xv[j];
            xv[j] = h;
            aprod *= a;
        }
        // (3) publish B_c (= zloc_31) and A_c, then release flag.
        reinterpret_cast<v2f*>(Bbuf)[c * (DCH / 2) + tid] = h;
    }
    if (tid == 0) Apub[c] = aprod;
    __syncthreads();   // compiler drains vmcnt before s_barrier: stores done
    if (tid == 0) {
        __threadfence();  // agent-scope release: cross-XCD visibility
        __hip_atomic_store(&flag[c], 1, __ATOMIC_RELEASE, __HIP_MEMORY_SCOPE_AGENT);
    }

    // (4) redundant b popcount + exclusive prefix over 512 segments.
    //     One segment per thread: 16 int4 loads (L2-warm). Overlaps the
    //     predecessors' publish in wall time.
    {
        const int4* bseg = reinterpret_cast<const int4*>(b) + tid * (SEG / 4);
        int v = 0;
#pragma unroll 4
        for (int q = 0; q < SEG / 4; ++q) {
            int4 w = bseg[q];
            v += w.x + w.y + w.z + w.w;
        }
        int incl = v;
#pragma unroll
        for (int off = 1; off < 64; off <<= 1) {
            int n = __shfl_up(incl, off, 64);
            if (lane >= off) incl += n;
        }
        if (lane == 63) wtot[wave] = incl;
        __syncthreads();
        int woff = 0;
        for (int w = 0; w < wave; ++w) woff += wtot[w];
        bpref[tid] = woff + incl - v;   // exclusive prefix
        if (tid == 0) bpref[NCHUNK] = L_COMP;
        __syncthreads();
    }

    // (5) rank-select this chunk's 33 pos values (threads 0..32)
    if (tid <= CHUNK) {
        int t = base + tid; // global one-rank (0-indexed)
        int posv = L_FULL;
        if (t < L_COMP) {
            int lo = 0, hi = NCHUNK;
            while (hi - lo > 1) {
                int mid = (lo + hi) >> 1;
                if (bpref[mid] <= t) lo = mid; else hi = mid;
            }
            int lr = t - bpref[lo]; // local rank within segment lo
            const int4* bseg = reinterpret_cast<const int4*>(b) + lo * (SEG / 4);
            int cnt = 0;
#pragma unroll 4
            for (int q = 0; q < SEG / 4; ++q) {
                int4 w = bseg[q];
                if (w.x) { if (cnt == lr) posv = lo * SEG + 4 * q + 0; ++cnt; }
                if (w.y) { if (cnt == lr) posv = lo * SEG + 4 * q + 1; ++cnt; }
                if (w.z) { if (cnt == lr) posv = lo * SEG + 4 * q + 2; ++cnt; }
                if (w.w) { if (cnt == lr) posv = lo * SEG + 4 * q + 3; ++cnt; }
            }
        }
        spos[tid] = posv;
    }
    __syncthreads();

    // (6) windowed flag-gated lookback: h_pre = sum_k w_k B_k; terms with
    //     w < WMIN dropped (same rule as R11-R15). W~1 on bench data;
    //     degrades gracefully to full lookback worst-case.
    v2f hpre = (v2f)0.f;
    {
        float w = 1.0f;
        const v2f* B2 = reinterpret_cast<const v2f*>(Bbuf) + tid;
        for (int k = c - 1; k >= 0; --k) {
            if (w < WMIN) break;    // uniform branch (w identical all lanes)
            while (__hip_atomic_load(&flag[k], __ATOMIC_ACQUIRE,
                                     __HIP_MEMORY_SCOPE_AGENT) == 0)
                __builtin_amdgcn_s_sleep(1);
            v2f bk = B2[(size_t)k * (DCH / 2)];   // ordered after acquire
            float ak = Apub[k];
            hpre += w * bk;
            w *= ak;
        }
    }

    // (7) register fixup: z_j = zloc_j + (prod_{t<=j} a_t) * h_pre.
    //     Recompute the uniform a-chain (L1-warm p) -> no extra VGPRs.
    {
        float ap = 1.0f;
#pragma unroll
        for (int j = 0; j < CHUNK; ++j) {
            float pt = clipp(p[base + j]);
            ap *= (1.0f - pt);
            xv[j] = xv[j] + ap * hpre;
        }
    }

    // (8) pure NT-store burst; nothing ever waits on these stores.
    {
        v2f* out2 = reinterpret_cast<v2f*>(out) + tid;
        int f0 = spos[0];
#pragma unroll
        for (int j = 0; j < CHUNK; ++j) {
            int f1 = spos[j + 1];               // LDS (lgkmcnt only)
            for (int f = f0; f < f1; ++f)
                __builtin_nontemporal_store(xv[j], &out2[(size_t)f * (DCH / 2)]);
            f0 = f1;
        }
    }
}

extern "C" void kernel_launch(void* const* d_in, const int* in_sizes, int n_in,
                              void* d_out, int out_size, void* d_ws, size_t ws_size,
                              hipStream_t stream) {
    const float* x = (const float*)d_in[0];
    const float* p = (const float*)d_in[1];
    const int* b = (const int*)d_in[2];
    float* out = (float*)d_out;

    char* ws = (char*)d_ws;
    float* Apub = (float*)ws;                  // NCHUNK floats (2 KiB)
    int* flag = (int*)(ws + 4096);             // NCHUNK ints (2 KiB)
    int* ticket = (int*)(ws + 6144);           // 1 int
    float* Bbuf = (float*)(ws + 8192);         // NCHUNK*DCH floats (2 MiB)

    // Reset flags + ticket every launch (ws is poisoned between iters).
    // hipMemsetAsync on the capture stream is graph-capture-safe (R12 ran).
    hipMemsetAsync(ws + 4096, 0, 4096, stream);
    fused_kernel<<<NCHUNK, NTHR, 0, stream>>>(x, p, b, out, Bbuf, Apub, flag, ticket);
}

// Round 8
// 219.695 us; speedup vs baseline: 1.1720x; 1.1720x over previous
//
#include <hip/hip_runtime.h>

// EMA chunked scan + inverse-gather broadcast for DeChunkLayer (R17).
// R17 = restructure: K1 = R13's proven stateless scan writing z (64 MiB ws,
// cached) + trivial idx[] build (NO rank-select); K2 = pure gather-broadcast
// stream at fill-like geometry (4096 tiny blocks, no LDS/sync/divergence).
//
// Evidence: fused-sync line dead (R12 110us, R16 120us kernels @1.5 TB/s —
// agent-scope acquire invalidates local L2; ~50us over stateless). Fixed
// harness calibrated twice: total-kernel = 134.7/137.0 => ~136us. All
// structures' kernel portion 63-69us vs ~33us traffic floor, and ALL
// scheduling levers (balance/occupancy/vmcnt-split) null. The fill kernel
// proves 6.9 TB/s at NINE % occupancy — pure stream, no prologue. Our
// streams always sit downstream of irregular per-block work (LDS scans,
// 33-lane serial rank-select, syncthreads chains). Fix: move ALL irregular
// work into tiny L2 tables (idx via cumsum — rank-select DELETED), make the
// output phase a literal copy kernel.
// Predict: WRITE +64MB (z), FETCH +20-50MB; K2 ~20-25us @ >5TB/s; total
// 198.6 -> 185-192. If >=198: prologue theory wrong -> revert R11, declare
// practical roofline (~63us kernel vs 33us floor, 136us fixed).
//
// x: (1, 16384, 1024) f32, p_selected: (16384,) f32, b: (1, 32768) i32
// out: (1, 32768, 1024) f32
// z_t = (1-p_t) z_{t-1} + p_t x_t  (p clipped to [1e-4, 1-1e-4])
// out[f] = z[idx[f]], idx = cumsum(b)-1
//
// ws layout: idx int[32768] @ 0 (128 KiB); z float[16384*1024] @ 128 KiB
// (64 MiB). If ws_size too small -> fallback: R13 stateless fused (proven).

#define DCH 1024
#define L_COMP 16384
#define L_FULL 32768
#define CHUNK 32
#define NCHUNK (L_COMP / CHUNK)   // 512
#define SEG (L_FULL / NCHUNK)     // 64 b-elements per segment
#define EPSV 1e-4f
#define WMIN 1e-12f               // ~2^-40 lookback window (matches R11-R16)
#define K2_ROWS 8                 // out rows per K2 block
#define WS_IDX_OFF 0
#define WS_Z_OFF (128 * 1024)
#define WS_NEED (WS_Z_OFF + (size_t)L_COMP * DCH * 4)

typedef float v4f __attribute__((ext_vector_type(4)));

__device__ __forceinline__ float clipp(float p) {
    p = fmaxf(p, EPSV);
    return fminf(p, 1.0f - EPSV);
}

// ---- K1: stateless windowed scan -> z; idx build (no rank-select).
__global__ __launch_bounds__(256, 2) void scan_kernel(
    const float* __restrict__ x, const float* __restrict__ p,
    const int* __restrict__ b, float* __restrict__ z, int* __restrict__ idx) {
    const int c = blockIdx.x;
    const int tid = threadIdx.x;
    const int lane = tid & 63;
    const int wave = tid >> 6;
    const int base = c * CHUNK;

    __shared__ int bpref[NCHUNK];
    __shared__ int wtot[4];

    // (c) window-find: walk chunk decay products backwards through p.
    //     Uniform scalar work; W~1 on bench; degrades to full replay.
    int kstart = c;
    {
        float w = 1.0f;
        while (kstart > 0 && w >= WMIN) {
            --kstart;
            float ap = 1.0f;
#pragma unroll 8
            for (int t = 0; t < CHUNK; ++t)
                ap *= (1.0f - clipp(p[kstart * CHUNK + t]));
            w *= ap;
        }
    }

    // (d) warmup scan from row kstart*32 with h=0: pure loads, no stores.
    const v4f* x4 = reinterpret_cast<const v4f*>(x) + tid;
    v4f h = (v4f)0.f;
    for (int r = kstart * CHUNK; r < base; r += 8) {
        v4f xw[8];
        float pw[8];
#pragma unroll
        for (int j = 0; j < 8; ++j) {
            xw[j] = x4[(size_t)(r + j) * (DCH / 4)];
            pw[j] = clipp(p[r + j]);            // uniform -> scalar
        }
#pragma unroll
        for (int j = 0; j < 8; ++j) {
            float a = 1.0f - pw[j];
            h = a * h + pw[j] * xw[j];
        }
    }

    // (e) own chunk: load/scan/store z rows (cached: K2 reads them via L3).
    {
        v4f* z4 = reinterpret_cast<v4f*>(z) + tid;
        for (int ib = 0; ib < CHUNK; ib += 8) {
            v4f xw[8];
            float pw[8];
#pragma unroll
            for (int j = 0; j < 8; ++j) {
                xw[j] = x4[(size_t)(base + ib + j) * (DCH / 4)];
                pw[j] = clipp(p[base + ib + j]);
            }
#pragma unroll
            for (int j = 0; j < 8; ++j) {
                float a = 1.0f - pw[j];
                h = a * h + pw[j] * xw[j];
                z4[(size_t)(base + ib + j) * (DCH / 4)] = h;
            }
        }
    }

    // (a) b popcount + exclusive prefix over 512 segments (2 per thread).
    {
        const int4* b4 = reinterpret_cast<const int4*>(b);
        int v0 = 0, v1 = 0;
#pragma unroll 4
        for (int q = 0; q < SEG / 4; ++q) {
            int4 w0 = b4[(2 * tid) * (SEG / 4) + q];
            int4 w1 = b4[(2 * tid + 1) * (SEG / 4) + q];
            v0 += w0.x + w0.y + w0.z + w0.w;
            v1 += w1.x + w1.y + w1.z + w1.w;
        }
        int s = v0 + v1;
        int incl = s;
#pragma unroll
        for (int off = 1; off < 64; off <<= 1) {
            int n = __shfl_up(incl, off, 64);
            if (lane >= off) incl += n;
        }
        if (lane == 63) wtot[wave] = incl;
        __syncthreads();
        int woff = 0;
        for (int w = 0; w < wave; ++w) woff += wtot[w];
        int ex = woff + incl - s;
        bpref[2 * tid] = ex;
        bpref[2 * tid + 1] = ex + v0;
        __syncthreads();
    }

    // (b) idx for this block's 64 out rows: idx[f] = bpref[c] + cumsum - 1.
    //     Replaces the old 33-thread binary-search + bit-sweep entirely.
    if (wave == 0) {
        int bv = b[c * SEG + lane];
        int incl = bv;
#pragma unroll
        for (int off = 1; off < 64; off <<= 1) {
            int n = __shfl_up(incl, off, 64);
            if (lane >= off) incl += n;
        }
        idx[c * SEG + lane] = bpref[c] + incl - 1;
    }
}

// ---- K2: pure gather-broadcast stream. No LDS, no sync, no divergence.
__global__ __launch_bounds__(256) void bcast_kernel(
    const float* __restrict__ z, const int* __restrict__ idx,
    float* __restrict__ out) {
    const int tid = threadIdx.x;
    const int r0 = blockIdx.x * K2_ROWS;

    int zi[K2_ROWS];
#pragma unroll
    for (int j = 0; j < K2_ROWS; ++j)
        zi[j] = idx[r0 + j];                  // uniform -> scalar loads

    const v4f* z4 = reinterpret_cast<const v4f*>(z) + tid;
    v4f v[K2_ROWS];
#pragma unroll
    for (int j = 0; j < K2_ROWS; ++j)
        v[j] = z4[(size_t)zi[j] * (DCH / 4)]; // L3/L2-warm gather

    v4f* out4 = reinterpret_cast<v4f*>(out) + tid;
#pragma unroll
    for (int j = 0; j < K2_ROWS; ++j)
        __builtin_nontemporal_store(v[j], &out4[(size_t)(r0 + j) * (DCH / 4)]);
}

// ---- Fallback (ws too small): R13 stateless fused, proven pass @204.2.
__global__ __launch_bounds__(256, 2) void fused_fallback(
    const float* __restrict__ x, const float* __restrict__ p,
    const int* __restrict__ b, float* __restrict__ out) {
    const int c = blockIdx.x;
    const int tid = threadIdx.x;
    const int lane = tid & 63;
    const int wave = tid >> 6;
    const int base = c * CHUNK;

    __shared__ int bpref[NCHUNK + 1];
    __shared__ int spos[CHUNK + 1];
    __shared__ int wtot[4];

    {
        const int4* b4 = reinterpret_cast<const int4*>(b);
        int v0 = 0, v1 = 0;
#pragma unroll 4
        for (int q = 0; q < SEG / 4; ++q) {
            int4 w0 = b4[(2 * tid) * (SEG / 4) + q];
            int4 w1 = b4[(2 * tid + 1) * (SEG / 4) + q];
            v0 += w0.x + w0.y + w0.z + w0.w;
            v1 += w1.x + w1.y + w1.z + w1.w;
        }
        int s = v0 + v1;
        int incl = s;
#pragma unroll
        for (int off = 1; off < 64; off <<= 1) {
            int n = __shfl_up(incl, off, 64);
            if (lane >= off) incl += n;
        }
        if (lane == 63) wtot[wave] = incl;
        __syncthreads();
        int woff = 0;
        for (int w = 0; w < wave; ++w) woff += wtot[w];
        int ex = woff + incl - s;
        bpref[2 * tid] = ex;
        bpref[2 * tid + 1] = ex + v0;
        if (tid == 0) bpref[NCHUNK] = L_COMP;
        __syncthreads();
    }
    if (tid <= CHUNK) {
        int t = base + tid;
        int posv = L_FULL;
        if (t < L_COMP) {
            int lo = 0, hi = NCHUNK;
            while (hi - lo > 1) {
                int mid = (lo + hi) >> 1;
                if (bpref[mid] <= t) lo = mid; else hi = mid;
            }
            int lr = t - bpref[lo];
            const int4* bseg = reinterpret_cast<const int4*>(b) + lo * (SEG / 4);
            int cnt = 0;
#pragma unroll 4
            for (int q = 0; q < SEG / 4; ++q) {
                int4 w = bseg[q];
                if (w.x) { if (cnt == lr) posv = lo * SEG + 4 * q + 0; ++cnt; }
                if (w.y) { if (cnt == lr) posv = lo * SEG + 4 * q + 1; ++cnt; }
                if (w.z) { if (cnt == lr) posv = lo * SEG + 4 * q + 2; ++cnt; }
                if (w.w) { if (cnt == lr) posv = lo * SEG + 4 * q + 3; ++cnt; }
            }
        }
        spos[tid] = posv;
    }
    __syncthreads();
    int kstart = c;
    {
        float w = 1.0f;
        while (kstart > 0 && w >= WMIN) {
            --kstart;
            float ap = 1.0f;
#pragma unroll 8
            for (int t = 0; t < CHUNK; ++t)
                ap *= (1.0f - clipp(p[kstart * CHUNK + t]));
            w *= ap;
        }
    }
    {
        const v4f* x4 = reinterpret_cast<const v4f*>(x) + tid;
        v4f h = (v4f)0.f;
        for (int r = kstart * CHUNK; r < base; r += 8) {
            v4f xv[8];
            float pv[8];
#pragma unroll
            for (int j = 0; j < 8; ++j) {
                xv[j] = x4[(size_t)(r + j) * (DCH / 4)];
                pv[j] = clipp(p[r + j]);
            }
#pragma unroll
            for (int j = 0; j < 8; ++j) {
                float a = 1.0f - pv[j];
                h = a * h + pv[j] * xv[j];
            }
        }
        v4f* out4 = reinterpret_cast<v4f*>(out) + tid;
        int f0 = spos[0];
        for (int ib = 0; ib < CHUNK; ib += 8) {
            v4f xv[8];
            float pv[8];
            int fe[8];
#pragma unroll
            for (int j = 0; j < 8; ++j) {
                xv[j] = x4[(size_t)(base + ib + j) * (DCH / 4)];
                pv[j] = clipp(p[base + ib + j]);
                fe[j] = spos[ib + j + 1];
            }
#pragma unroll
            for (int j = 0; j < 8; ++j) {
                float a = 1.0f - pv[j];
                h = a * h + pv[j] * xv[j];
                for (int f = f0; f < fe[j]; ++f)
                    __builtin_nontemporal_store(h, &out4[(size_t)f * (DCH / 4)]);
                f0 = fe[j];
            }
        }
    }
}

extern "C" void kernel_launch(void* const* d_in, const int* in_sizes, int n_in,
                              void* d_out, int out_size, void* d_ws, size_t ws_size,
                              hipStream_t stream) {
    const float* x = (const float*)d_in[0];
    const float* p = (const float*)d_in[1];
    const int* b = (const int*)d_in[2];
    float* out = (float*)d_out;

    if (ws_size >= WS_NEED) {
        char* ws = (char*)d_ws;
        int* idx = (int*)(ws + WS_IDX_OFF);     // 128 KiB
        float* z = (float*)(ws + WS_Z_OFF);     // 64 MiB
        scan_kernel<<<NCHUNK, 256, 0, stream>>>(x, p, b, z, idx);
        bcast_kernel<<<L_FULL / K2_ROWS, 256, 0, stream>>>(z, idx, out);
    } else {
        fused_fallback<<<NCHUNK, 256, 0, stream>>>(x, p, b, out);
    }
}

// Round 10
// 205.563 us; speedup vs baseline: 1.2525x; 1.0687x over previous
//
#include <hip/hip_runtime.h>

// EMA chunked scan + inverse-gather broadcast for DeChunkLayer (R19).
// R19 = R18 resubmitted (bench infra failed: "container failed twice", no
// kernel signal). Static audit found no hang/fault path: no spin-waits, all
// loops bounded, idx non-decreasing in [0,L_COMP), ws 128 KiB + fallback.
//
// R18 design: out-centric restructure. K0 (one tiny block) builds
// idx[]=cumsum(b)-1 into a 128 KiB L2 table; K2 blocks own 64 CONSECUTIVE
// out rows each (stores grid-linear, fill-geometry), recompute their z
// window from x,p statelessly (R13-proven numerics, row-granular window,
// same WMIN=1e-12 dropped-term bound as R11-R17).
//
// Evidence: R17's z round-trip cost its bytes at ~6 TB/s (delta matched
// model) -> marginal BW fine; absolute kernel BW stuck ~3.3 TB/s.
// FETCH~34MB << x's 64MiB => x is L3-RESIDENT across iters; HBM floor
// ~24-28us. Remaining structural difference vs the 6.9 TB/s fill: per-block
// irregular prologue (redundant 128KiB b sweep x512, LDS scan, 2-4
// syncthreads, 33-lane serial rank-select) and variable store counts
// (0..~110 rows/block). This deletes ALL of it from the streaming kernel:
// no b reads, no LDS scan, no rank-select; stores exactly 256 KiB per
// block, linear across the grid.
// Predict: K0 4-6us, main ~45-52us => dur 198.6-best -> ~183-192.
// If >=198.6: irregularity theory dead -> restore R11, declare ceiling.
//
// x: (1, 16384, 1024) f32, p_selected: (16384,) f32, b: (1, 32768) i32
// out: (1, 32768, 1024) f32
// z_t = (1-p_t) z_{t-1} + p_t x_t  (p clipped to [1e-4, 1-1e-4])
// out[f] = z[idx[f]], idx = cumsum(b)-1
//
// ws: idx int[32768] @ 0 (128 KiB). If ws too small -> R13 fallback (proven).

#define DCH 1024
#define L_COMP 16384
#define L_FULL 32768
#define CHUNK 32
#define NCHUNK (L_COMP / CHUNK)   // 512
#define SEG (L_FULL / NCHUNK)     // 64
#define ROWS_PER_BLK 64           // out rows per K2 block
#define NBLK (L_FULL / ROWS_PER_BLK) // 512
#define EPSV 1e-4f
#define WMIN 1e-12f               // ~2^-40 dropped-term bound (R11-R17)
#define WS_NEED ((size_t)L_FULL * 4)

typedef float v4f __attribute__((ext_vector_type(4)));

__device__ __forceinline__ float clipp(float p) {
    p = fmaxf(p, EPSV);
    return fminf(p, 1.0f - EPSV);
}

// ---- K0: idx[f] = cumsum(b)[f] - 1. One block, 1024 threads, 32 elems each.
__global__ __launch_bounds__(1024) void idx_kernel(
    const int* __restrict__ b, int* __restrict__ idx) {
    const int tid = threadIdx.x;
    const int lane = tid & 63;
    const int wave = tid >> 6;          // 0..15
    __shared__ int wtot[16];

    int4 rb[8];
    const int4* b4 = reinterpret_cast<const int4*>(b) + tid * 8;
#pragma unroll
    for (int q = 0; q < 8; ++q) rb[q] = b4[q];
    int s = 0;
#pragma unroll
    for (int q = 0; q < 8; ++q) s += rb[q].x + rb[q].y + rb[q].z + rb[q].w;
    int incl = s;
#pragma unroll
    for (int off = 1; off < 64; off <<= 1) {
        int n = __shfl_up(incl, off, 64);
        if (lane >= off) incl += n;
    }
    if (lane == 63) wtot[wave] = incl;
    __syncthreads();
    int woff = 0;
    for (int w = 0; w < wave; ++w) woff += wtot[w];
    int cum = woff + incl - s;          // exclusive prefix of this thread
    int* op = idx + tid * 32;
#pragma unroll
    for (int q = 0; q < 8; ++q) {
        cum += rb[q].x; op[4 * q + 0] = cum - 1;
        cum += rb[q].y; op[4 * q + 1] = cum - 1;
        cum += rb[q].z; op[4 * q + 2] = cum - 1;
        cum += rb[q].w; op[4 * q + 3] = cum - 1;
    }
}

// ---- K2: out-centric stateless scan+broadcast. No b reads, no LDS scan,
//          no rank-select; stores exactly 64 consecutive rows per block.
__global__ __launch_bounds__(256, 2) void bcast_scan_kernel(
    const float* __restrict__ x, const float* __restrict__ p,
    const int* __restrict__ idx, float* __restrict__ out) {
    const int tid = threadIdx.x;
    const int r0 = blockIdx.x * ROWS_PER_BLK;
    __shared__ int sidx[ROWS_PER_BLK];

    if (tid < ROWS_PER_BLK) sidx[tid] = idx[r0 + tid];
    __syncthreads();
    const int tmin = sidx[0];
    const int tmax = sidx[ROWS_PER_BLK - 1];

    // window walk: row-granular, batched 16 scalar p loads (uniform).
    // Batch overshoot only ENLARGES the window (safer numerics).
    int s0 = tmin;
    {
        float w = 1.0f;
        while (s0 > 0 && w >= WMIN) {
            if (s0 >= 16) {
                float pw[16];
#pragma unroll
                for (int j = 0; j < 16; ++j) pw[j] = clipp(p[s0 - 16 + j]);
#pragma unroll
                for (int j = 0; j < 16; ++j) w *= (1.0f - pw[j]);
                s0 -= 16;
            } else {
                for (int j = 0; j < s0; ++j) w *= (1.0f - clipp(p[j]));
                s0 = 0;
            }
        }
    }

    // warmup scan rows [s0, tmin): pure loads (x L3-warm), no stores.
    const v4f* x4 = reinterpret_cast<const v4f*>(x) + tid;
    v4f h = (v4f)0.f;
    int r = s0;
    for (; r + 8 <= tmin; r += 8) {
        v4f xw[8];
        float pw[8];
#pragma unroll
        for (int j = 0; j < 8; ++j) {
            xw[j] = x4[(size_t)(r + j) * (DCH / 4)];
            pw[j] = clipp(p[r + j]);            // uniform -> scalar
        }
#pragma unroll
        for (int j = 0; j < 8; ++j) {
            float a = 1.0f - pw[j];
            h = a * h + pw[j] * xw[j];
        }
    }
    for (; r < tmin; ++r) {
        v4f xw = x4[(size_t)r * (DCH / 4)];
        float pw = clipp(p[r]);
        h = (1.0f - pw) * h + pw * xw;
    }

    // main scan t in [tmin, tmax]; store h to the contiguous run of out
    // rows with sidx[j]==t (j advances monotonically; uniform branch).
    v4f* out4 = reinterpret_cast<v4f*>(out) + tid;
    int j = 0;
    int t = tmin;
    for (; t + 8 <= tmax + 1; t += 8) {
        v4f xw[8];
        float pw[8];
#pragma unroll
        for (int q = 0; q < 8; ++q) {
            xw[q] = x4[(size_t)(t + q) * (DCH / 4)];
            pw[q] = clipp(p[t + q]);
        }
#pragma unroll
        for (int q = 0; q < 8; ++q) {
            float a = 1.0f - pw[q];
            h = a * h + pw[q] * xw[q];
            while (j < ROWS_PER_BLK && sidx[j] == t + q) {
                __builtin_nontemporal_store(h, &out4[(size_t)(r0 + j) * (DCH / 4)]);
                ++j;
            }
        }
    }
    for (; t <= tmax; ++t) {
        v4f xw = x4[(size_t)t * (DCH / 4)];
        float pw = clipp(p[t]);
        h = (1.0f - pw) * h + pw * xw;
        while (j < ROWS_PER_BLK && sidx[j] == t) {
            __builtin_nontemporal_store(h, &out4[(size_t)(r0 + j) * (DCH / 4)]);
            ++j;
        }
    }
}

// ---- Fallback (ws too small): R13 stateless fused, proven pass @204.2.
__global__ __launch_bounds__(256, 2) void fused_fallback(
    const float* __restrict__ x, const float* __restrict__ p,
    const int* __restrict__ b, float* __restrict__ out) {
    const int c = blockIdx.x;
    const int tid = threadIdx.x;
    const int lane = tid & 63;
    const int wave = tid >> 6;
    const int base = c * CHUNK;

    __shared__ int bpref[NCHUNK + 1];
    __shared__ int spos[CHUNK + 1];
    __shared__ int wtot[4];

    {
        const int4* b4 = reinterpret_cast<const int4*>(b);
        int v0 = 0, v1 = 0;
#pragma unroll 4
        for (int q = 0; q < SEG / 4; ++q) {
            int4 w0 = b4[(2 * tid) * (SEG / 4) + q];
            int4 w1 = b4[(2 * tid + 1) * (SEG / 4) + q];
            v0 += w0.x + w0.y + w0.z + w0.w;
            v1 += w1.x + w1.y + w1.z + w1.w;
        }
        int s = v0 + v1;
        int incl = s;
#pragma unroll
        for (int off = 1; off < 64; off <<= 1) {
            int n = __shfl_up(incl, off, 64);
            if (lane >= off) incl += n;
        }
        if (lane == 63) wtot[wave] = incl;
        __syncthreads();
        int woff = 0;
        for (int w = 0; w < wave; ++w) woff += wtot[w];
        int ex = woff + incl - s;
        bpref[2 * tid] = ex;
        bpref[2 * tid + 1] = ex + v0;
        if (tid == 0) bpref[NCHUNK] = L_COMP;
        __syncthreads();
    }
    if (tid <= CHUNK) {
        int t = base + tid;
        int posv = L_FULL;
        if (t < L_COMP) {
            int lo = 0, hi = NCHUNK;
            while (hi - lo > 1) {
                int mid = (lo + hi) >> 1;
                if (bpref[mid] <= t) lo = mid; else hi = mid;
            }
            int lr = t - bpref[lo];
            const int4* bseg = reinterpret_cast<const int4*>(b) + lo * (SEG / 4);
            int cnt = 0;
#pragma unroll 4
            for (int q = 0; q < SEG / 4; ++q) {
                int4 w = bseg[q];
                if (w.x) { if (cnt == lr) posv = lo * SEG + 4 * q + 0; ++cnt; }
                if (w.y) { if (cnt == lr) posv = lo * SEG + 4 * q + 1; ++cnt; }
                if (w.z) { if (cnt == lr) posv = lo * SEG + 4 * q + 2; ++cnt; }
                if (w.w) { if (cnt == lr) posv = lo * SEG + 4 * q + 3; ++cnt; }
            }
        }
        spos[tid] = posv;
    }
    __syncthreads();
    int kstart = c;
    {
        float w = 1.0f;
        while (kstart > 0 && w >= WMIN) {
            --kstart;
            float ap = 1.0f;
#pragma unroll 8
            for (int t = 0; t < CHUNK; ++t)
                ap *= (1.0f - clipp(p[kstart * CHUNK + t]));
            w *= ap;
        }
    }
    {
        const v4f* x4 = reinterpret_cast<const v4f*>(x) + tid;
        v4f h = (v4f)0.f;
        for (int r = kstart * CHUNK; r < base; r += 8) {
            v4f xv[8];
            float pv[8];
#pragma unroll
            for (int j = 0; j < 8; ++j) {
                xv[j] = x4[(size_t)(r + j) * (DCH / 4)];
                pv[j] = clipp(p[r + j]);
            }
#pragma unroll
            for (int j = 0; j < 8; ++j) {
                float a = 1.0f - pv[j];
                h = a * h + pv[j] * xv[j];
            }
        }
        v4f* out4 = reinterpret_cast<v4f*>(out) + tid;
        int f0 = spos[0];
        for (int ib = 0; ib < CHUNK; ib += 8) {
            v4f xv[8];
            float pv[8];
            int fe[8];
#pragma unroll
            for (int j = 0; j < 8; ++j) {
                xv[j] = x4[(size_t)(base + ib + j) * (DCH / 4)];
                pv[j] = clipp(p[base + ib + j]);
                fe[j] = spos[ib + j + 1];
            }
#pragma unroll
            for (int j = 0; j < 8; ++j) {
                float a = 1.0f - pv[j];
                h = a * h + pv[j] * xv[j];
                for (int f = f0; f < fe[j]; ++f)
                    __builtin_nontemporal_store(h, &out4[(size_t)f * (DCH / 4)]);
                f0 = fe[j];
            }
        }
    }
}

extern "C" void kernel_launch(void* const* d_in, const int* in_sizes, int n_in,
                              void* d_out, int out_size, void* d_ws, size_t ws_size,
                              hipStream_t stream) {
    const float* x = (const float*)d_in[0];
    const float* p = (const float*)d_in[1];
    const int* b = (const int*)d_in[2];
    float* out = (float*)d_out;

    if (ws_size >= WS_NEED) {
        int* idx = (int*)d_ws;                  // 128 KiB, rebuilt each launch
        idx_kernel<<<1, 1024, 0, stream>>>(b, idx);
        bcast_scan_kernel<<<NBLK, 256, 0, stream>>>(x, p, idx, out);
    } else {
        fused_fallback<<<NCHUNK, 256, 0, stream>>>(x, p, b, out);
    }
}

// Round 11
// 198.266 us; speedup vs baseline: 1.2986x; 1.0368x over previous
//
#include <hip/hip_runtime.h>

// EMA chunked scan + inverse-gather broadcast for DeChunkLayer (R20).
// R20 = RESTORE of R11 (session best, 198.6 us, verified Round 2). The
// working tree held R19 (205.6); this puts the best kernel back as final.
//
// Session evidence ledger (kernel portion ~= dur - ~136 us fixed harness):
//   R11 2-kernel windowed replay ....... 198.6  (kernel ~63 us)  << BEST
//   R13 stateless fused ................ 204.2  (~68)
//   R15 fused + phase-split ............ 205.0  (~69)
//   R19 out-centric grid-linear ........ 205.6  (~70)
//   R17 z-materialized ................. 219.7  (~84)
//   R12/R16 flag-lookback sync ......... 244.7/257.5 (sync poison)
// Falsified levers: block balance (R10 null), occupancy 2x (R14 null),
// vmcnt load/store entanglement (R15 null), cross-block release/acquire
// (R12/R16 -50us), extra materialization (R17 costs its bytes), prologue
// irregularity/store regularity (R18/R19 null). Marginal bytes move at
// ~6 TB/s; a ~30us structure-independent base survives all structures.
//
// x: (1, 16384, 1024) f32, p_selected: (16384,) f32, b: (1, 32768) i32
// out: (1, 32768, 1024) f32
// z_t = (1-p_t) z_{t-1} + p_t x_t  (p clipped to [1e-4, 1-1e-4])
// out[f] = z[t] for f in [pos[t], pos[t+1])
//
// K1: per-chunk local scan -> Bbuf/Abuf; per-segment b popcount -> bsum.
// K2: bpref+log2A scans + rank-select pos + numerically-windowed replay
//     (terms with weight < 2^-40 dropped; data-adaptive, worst case = full
//     replay) + final scan + ranged broadcast writes (nontemporal).

#define DCH 1024
#define L_COMP 16384
#define L_FULL 32768
#define CHUNK 32
#define NCHUNK (L_COMP / CHUNK)   // 512
#define SEG (L_FULL / NCHUNK)     // 64 b-elements per block
#define EPSV 1e-4f
#define LOG2_THRESH 40.0f         // drop replay terms with weight < 2^-40

typedef float v4f __attribute__((ext_vector_type(4)));

__device__ __forceinline__ float clipp(float p) {
    p = fmaxf(p, EPSV);
    return fminf(p, 1.0f - EPSV);
}

// ---- K1: chunk-local scan (zero init) -> Bbuf[c], Abuf[c]; b segment sums
__global__ __launch_bounds__(256, 2) void chunk_kernel(
    const float* __restrict__ x, const float* __restrict__ p,
    const int* __restrict__ b,
    float* __restrict__ Bbuf, float* __restrict__ Abuf, int* __restrict__ bsum) {
    const int c = blockIdx.x;
    const int tid = threadIdx.x;
    const int lane = tid & 63;
    const int wave = tid >> 6;
    const int base = c * CHUNK;

    const v4f* x4 = reinterpret_cast<const v4f*>(x) + (size_t)base * (DCH / 4) + tid;
    v4f h = (v4f)0.f;
    float aprod = 1.0f;
    for (int ib = 0; ib < CHUNK; ib += 8) {
        v4f xv[8];
        float pv[8];
#pragma unroll
        for (int j = 0; j < 8; ++j) {
            xv[j] = x4[(ib + j) * (DCH / 4)];
            pv[j] = clipp(p[base + ib + j]); // uniform -> scalar load
        }
#pragma unroll
        for (int j = 0; j < 8; ++j) {
            float a = 1.0f - pv[j];
            h = a * h + pv[j] * xv[j];
            aprod *= a;
        }
    }
    reinterpret_cast<v4f*>(Bbuf)[c * (DCH / 4) + tid] = h;
    if (tid == 0) Abuf[c] = aprod;
    if (wave == 0) {
        int v = b[c * SEG + lane];
        int s = v;
#pragma unroll
        for (int off = 1; off < 64; off <<= 1) s += __shfl_xor(s, off, 64);
        if (lane == 0) bsum[c] = s;
    }
}

// ---- K2: bpref+log2A scans + rank-select pos + windowed replay + scan/write
__global__ __launch_bounds__(256, 2) void dechunk_kernel(
    const float* __restrict__ x, const float* __restrict__ p,
    const int* __restrict__ b, float* __restrict__ out,
    const float* __restrict__ Bbuf, const float* __restrict__ Abuf,
    const int* __restrict__ bsum) {
    const int c = blockIdx.x;
    const int tid = threadIdx.x;
    const int lane = tid & 63;
    const int wave = tid >> 6;
    const int base = c * CHUNK;

    __shared__ int bpref[NCHUNK + 1];
    __shared__ float lapref[NCHUNK + 1];  // exclusive prefix of log2(A)
    __shared__ int spos[CHUNK + 1];
    __shared__ int wtot[4];
    __shared__ float wtotf[4];

    // (a) block-local exclusive prefixes over the 512 segment sums (int)
    //     and the 512 log2-decay values (float), fused in one butterfly.
    {
        int v0 = bsum[2 * tid];
        int v1 = bsum[2 * tid + 1];
        // clamp at -1000: A==0 (underflow) must not produce -inf - -inf = NaN
        // in the exclusive-scan subtraction; -1000/chunk >> LOG2_THRESH keeps
        // the windowing semantics exact (older terms dropped).
        float l0 = fmaxf(log2f(Abuf[2 * tid]), -1000.0f);
        float l1 = fmaxf(log2f(Abuf[2 * tid + 1]), -1000.0f);
        int s = v0 + v1;
        float ls = l0 + l1;
        int incl = s;
        float lincl = ls;
#pragma unroll
        for (int off = 1; off < 64; off <<= 1) {
            int n = __shfl_up(incl, off, 64);
            float lf = __shfl_up(lincl, off, 64);
            if (lane >= off) { incl += n; lincl += lf; }
        }
        if (lane == 63) { wtot[wave] = incl; wtotf[wave] = lincl; }
        __syncthreads();
        int woff = 0;
        float lwoff = 0.0f;
        for (int w = 0; w < wave; ++w) { woff += wtot[w]; lwoff += wtotf[w]; }
        int ex = woff + incl - s;        // exclusive prefix of this pair
        float lex = lwoff + lincl - ls;
        bpref[2 * tid] = ex;
        bpref[2 * tid + 1] = ex + v0;
        lapref[2 * tid] = lex;
        lapref[2 * tid + 1] = lex + l0;
        if (tid == 0) bpref[NCHUNK] = L_COMP;
        __syncthreads();
    }

    // (b) rank-select this chunk's 33 pos values (threads 0..32)
    if (tid <= CHUNK) {
        int t = base + tid; // global one-rank (0-indexed)
        int posv = L_FULL;
        if (t < L_COMP) {
            int lo = 0, hi = NCHUNK;
            while (hi - lo > 1) {
                int mid = (lo + hi) >> 1;
                if (bpref[mid] <= t) lo = mid; else hi = mid;
            }
            int lr = t - bpref[lo]; // local rank within segment lo
            const int4* bseg = reinterpret_cast<const int4*>(b) + lo * (SEG / 4);
            int cnt = 0;
#pragma unroll 4
            for (int q = 0; q < SEG / 4; ++q) {
                int4 w = bseg[q];
                if (w.x) { if (cnt == lr) posv = lo * SEG + 4 * q + 0; ++cnt; }
                if (w.y) { if (cnt == lr) posv = lo * SEG + 4 * q + 1; ++cnt; }
                if (w.z) { if (cnt == lr) posv = lo * SEG + 4 * q + 2; ++cnt; }
                if (w.w) { if (cnt == lr) posv = lo * SEG + 4 * q + 3; ++cnt; }
            }
        }
        spos[tid] = posv;
    }

    // (c) windowed interchunk replay: h = state before chunk c.
    //     Weight of chunk k is 2^(lapref[c] - lapref[k+1]); keep only terms
    //     >= 2^-LOG2_THRESH. lapref is non-increasing -> kept set is a
    //     suffix [kstart, c-1]; binary search its start. Uniform per block.
    v4f h = (v4f)0.f;
    {
        const float lim = lapref[c] + LOG2_THRESH;
        int kstart = 0;
        if (lapref[0] > lim) {
            int lo = 0, hi = c; // lapref[lo] > lim, lapref[hi] <= lim
            while (hi - lo > 1) {
                int mid = (lo + hi) >> 1;
                if (lapref[mid] > lim) lo = mid; else hi = mid;
            }
            kstart = hi - 1; // include one boundary term (weight may be tiny)
        }
        const v4f* B4 = reinterpret_cast<const v4f*>(Bbuf) + tid;
        int k = kstart;
        for (; k + 16 <= c; k += 16) {
            v4f bv[16];
            float av[16];
#pragma unroll
            for (int j = 0; j < 16; ++j) {
                bv[j] = B4[(k + j) * (DCH / 4)];
                av[j] = Abuf[k + j]; // uniform -> scalar load
            }
#pragma unroll
            for (int j = 0; j < 16; ++j)
                h = av[j] * h + bv[j];
        }
        for (; k < c; ++k) {
            v4f bv = B4[k * (DCH / 4)];
            h = Abuf[k] * h + bv;
        }
    }
    __syncthreads();

    // (d) final scan of chunk c with true init; ranged broadcast writes (NT)
    {
        const v4f* x4 = reinterpret_cast<const v4f*>(x) + (size_t)base * (DCH / 4) + tid;
        v4f* out4 = reinterpret_cast<v4f*>(out) + tid;
        int f0 = spos[0];
        for (int ib = 0; ib < CHUNK; ib += 8) {
            v4f xv[8];
            float pv[8];
            int fe[8];
#pragma unroll
            for (int j = 0; j < 8; ++j) {
                xv[j] = x4[(ib + j) * (DCH / 4)];   // cached: L3-warm x
                pv[j] = clipp(p[base + ib + j]);    // uniform -> scalar
                fe[j] = spos[ib + j + 1];           // LDS
            }
#pragma unroll
            for (int j = 0; j < 8; ++j) {
                float a = 1.0f - pv[j];
                h = a * h + pv[j] * xv[j];
                for (int f = f0; f < fe[j]; ++f) {
                    __builtin_nontemporal_store(h, &out4[(size_t)f * (DCH / 4)]);
                }
                f0 = fe[j];
            }
        }
    }
}

extern "C" void kernel_launch(void* const* d_in, const int* in_sizes, int n_in,
                              void* d_out, int out_size, void* d_ws, size_t ws_size,
                              hipStream_t stream) {
    const float* x = (const float*)d_in[0];
    const float* p = (const float*)d_in[1];
    const int* b = (const int*)d_in[2];
    float* out = (float*)d_out;

    char* ws = (char*)d_ws;
    float* Abuf = (float*)ws;                  // NCHUNK floats (2 KiB)
    int* bsum = (int*)(ws + 4096);             // NCHUNK ints (2 KiB)
    float* Bbuf = (float*)(ws + 8192);         // NCHUNK*DCH floats (2 MiB), 16B aligned

    chunk_kernel<<<NCHUNK, 256, 0, stream>>>(x, p, b, Bbuf, Abuf, bsum);
    dechunk_kernel<<<NCHUNK, 256, 0, stream>>>(x, p, b, out, Bbuf, Abuf, bsum);
}